// Round 9
// baseline (258.512 us; speedup 1.0000x reference)
//
#include <hip/hip_runtime.h>
#include <stdint.h>

// ---------------------------------------------------------------------------
// MS_SSA_Conv: spiking self-attention. T=4 B=8 C=384 N=1024 heads=8.
// R12: qkv occupancy fix. R11 counters: MfmaUtil 27%, VALU 21%, LDS ~55%,
// Occupancy 17.6% (LDS 149KB -> 1 block/CU = 2 waves/SIMD) -> latency-bound.
// New qkv geometry: BM=128, BN=128 (4t x 32n), BK=32, 256 thr (4 waves 2x2,
// wave-tile 64x64 -> same LDS traffic/FLOP), ring-of-3 = 50.7KB LDS ->
// 3 blocks/CU, 12 waves/CU (1.5x TLP). Grid 32x9x8 = 2304 = exactly 3
// co-residency rounds. 64B-row swizzle chunk^=(row>>1)&3 (conflict-free by
// the bank model that explains both R4's 5.3M conflicts and R9's 0).
// Counted vmcnt(4) publish, stage(T+2), one barrier/tile (R9 discipline).
// K-order unchanged (ascending 32-chunks) -> bit-identical output.
// All other kernels: R11 verbatim.
// ---------------------------------------------------------------------------

typedef unsigned short u16;
typedef __attribute__((ext_vector_type(8))) short short8v;
typedef __attribute__((ext_vector_type(4))) float f32x4;

#define AS1 __attribute__((address_space(1)))
#define AS3 __attribute__((address_space(3)))

__device__ __forceinline__ void async16(const void* g, void* l) {
    __builtin_amdgcn_global_load_lds((const AS1 unsigned int*)g,
                                     (AS3 unsigned int*)l, 16, 0, 0);
}
__device__ __forceinline__ f32x4 mfma_bf16(short8v a, short8v b, f32x4 c) {
    return __builtin_amdgcn_mfma_f32_16x16x32_bf16(a, b, c, 0, 0, 0);
}
__device__ __forceinline__ f32x4 mfma_f16(short8v a, short8v b, f32x4 c) {
    return __builtin_amdgcn_mfma_f32_16x16x32_f16(a, b, c, 0, 0, 0);
}

__device__ __forceinline__ u16 f2bf(float f) {  // RNE fp32->bf16
    uint32_t x = __float_as_uint(f);
    return (u16)((x + 0x7FFFu + ((x >> 16) & 1u)) >> 16);
}

#define SPIKE_H ((u16)0x3C00)  // fp16 1.0 (xs)
#define SPIKE_B ((u16)0x3F80)  // bf16 1.0 (q/k/v spikes, kvs mask)

// ---------------------------------------------------------------------------
// K0: weights. Ah [1152][768] fp16 2-part split (part-major cols);
// Aproj [384][384] bf16.
// ---------------------------------------------------------------------------
__global__ void prep_kernel(const float* __restrict__ qw, const float* __restrict__ kw,
                            const float* __restrict__ vw, const float* __restrict__ pw,
                            u16* __restrict__ Ah, u16* __restrict__ Aproj) {
    int id = blockIdx.x * 256 + threadIdx.x;
    if (id >= 1152 * 384) return;
    int m = id / 384, c = id % 384;
    int br = m / 384, o = m % 384;
    const float* W = (br == 0) ? qw : (br == 1) ? kw : vw;
    float w = W[o * 384 + c];
    union H { _Float16 h; u16 u; } u0, u1;
    u0.h = (_Float16)w;
    float r1 = w - (float)u0.h;
    u1.h = (_Float16)r1;
    u16* row = Ah + (size_t)m * 768;
    row[c] = u0.u;
    row[384 + c] = u1.u;
    if (br == 0) Aproj[o * 384 + c] = f2bf(pw[o * 384 + c]);
}

// ---------------------------------------------------------------------------
// K1: shortcut LIF on x -> xs[t,b,n,c] fp16 spikes.
// ---------------------------------------------------------------------------
__global__ __launch_bounds__(256) void lifx_kernel(const float* __restrict__ x,
                                                   u16* __restrict__ xs) {
    __shared__ u16 Tr[64 * 72];
    int b = blockIdx.z, c0 = blockIdx.y * 64, n0 = blockIdx.x * 64;
    int tid = threadIdx.x;
    int nj = (tid & 15) * 4;
    int ci = tid >> 4;
    float v[4][4];
#pragma unroll
    for (int p = 0; p < 4; p++)
#pragma unroll
        for (int e = 0; e < 4; e++) v[p][e] = 0.0f;

    for (int t = 0; t < 4; t++) {
#pragma unroll
        for (int p = 0; p < 4; p++) {
            const float* src = x + ((size_t)((t * 8 + b) * 384 + c0 + p * 16 + ci)) * 1024 + n0 + nj;
            float4 xv = *(const float4*)src;
            float xa[4] = {xv.x, xv.y, xv.z, xv.w};
#pragma unroll
            for (int e = 0; e < 4; e++) {
                float vv = v[p][e];
                vv = __fadd_rn(vv, __fmul_rn(__fsub_rn(xa[e], vv), 0.5f));
                bool sp = (vv >= 0.5f);
                v[p][e] = sp ? 0.0f : vv;
                Tr[(nj + e) * 72 + p * 16 + ci] = sp ? SPIKE_H : (u16)0;
            }
        }
        __syncthreads();
#pragma unroll
        for (int p = 0; p < 4; p++) {
            int nr = p * 16 + (tid >> 4);
            int c4 = (tid & 15) * 4;
            *(ushort4*)(xs + ((size_t)((t * 8 + b) * 1024 + n0 + nr)) * 384 + c0 + c4) =
                *(const ushort4*)&Tr[nr * 72 + c4];
        }
        __syncthreads();
    }
}

// ---------------------------------------------------------------------------
// K2: QKV conv (2-part fp16, K=768) + BN + LIF over t (from acc, epilogue).
// BM=128, BN=128 (4t x 32n), BK=32, ring-of-3 (50.7KB -> 3 blocks/CU),
// 4 waves 2Mx2N (wave-tile 64x64), counted vmcnt(4), 1 barrier/tile.
// 64B rows, swizzle chunk^=(row>>1)&3 (conflict-free). grid (32, 9, 8).
// ---------------------------------------------------------------------------
__global__ __launch_bounds__(256, 2) void qkv_kernel(
    const u16* __restrict__ Ah, const u16* __restrict__ xs,
    u16* __restrict__ qs, u16* __restrict__ ks, u16* __restrict__ vs,
    const float* __restrict__ qg, const float* __restrict__ qb, const float* __restrict__ qm, const float* __restrict__ qv,
    const float* __restrict__ kg, const float* __restrict__ kb, const float* __restrict__ km, const float* __restrict__ kvr,
    const float* __restrict__ vg, const float* __restrict__ vb, const float* __restrict__ vm, const float* __restrict__ vvr) {
    __shared__ __align__(16) u16 As[3][4096];   // [slot][128 rows x 32 k] 8KB
    __shared__ __align__(16) u16 Bs[3][4096];   // [slot][128 cols x 32 k] 8KB
    __shared__ float bnS[128], bnM[128], bnB[128];

    const int b = blockIdx.z, mt = blockIdx.y, nt = blockIdx.x;
    const int m0 = mt * 128, n0 = nt * 32;
    const int branch = mt / 3, o0 = (mt % 3) * 128;
    const int tid = threadIdx.x, wave = tid >> 6, lane = tid & 63;
    const int l15 = lane & 15, quad = lane >> 4;
    const int wm2 = wave >> 1;   // 0/1: 64-row half
    const int wn2 = wave & 1;    // 0/1: 64-col half (4t x 16n)

    const float* g_  = (branch == 0) ? qg : (branch == 1) ? kg : vg;
    const float* be_ = (branch == 0) ? qb : (branch == 1) ? kb : vb;
    const float* m_  = (branch == 0) ? qm : (branch == 1) ? km : vm;
    const float* v_  = (branch == 0) ? qv : (branch == 1) ? kvr : vvr;
    u16* dstp = (branch == 0) ? qs : (branch == 1) ? ks : vs;

    if (tid < 128) {
        int o = o0 + tid;
        bnS[tid] = g_[o] / sqrtf(v_[o] + 1e-5f);
        bnM[tid] = m_[o];
        bnB[tid] = be_[o];
    }

    // staging: 2 A-loads + 2 B-loads per thread per stage (4 = vmcnt unit).
    // load l covers (row/col = l*... : rows 0..63 then 64..127), 64B rows,
    // 4 chunks of 16B; source chunk pre-swizzled with (row>>1)&3 (involution
    // with the read side; +64 rows doesn't change (row>>1)&3).
    const int srow = tid >> 2;                         // 0..63
    const int cs8 = ((tid & 3) ^ ((srow >> 1) & 3)) * 8;
    const int dst0 = tid * 8;                          // linear LDS dest (u16)

    const u16* pA0 = Ah + (size_t)(m0 + srow) * 768 + cs8;        // rows 0..63
    const u16* pA1 = Ah + (size_t)(m0 + 64 + srow) * 768 + cs8;   // rows 64..127
    // col C: t = (C>>4)&3, n = (C>>6)*16 + (C&15); cols 0..63 / 64..127
    const int tB = (srow >> 4) & 3, nB = srow & 15;
    const u16* pB0 = xs + ((size_t)((tB * 8 + b) * 1024 + n0 + nB)) * 384 + cs8;
    const u16* pB1 = xs + ((size_t)((tB * 8 + b) * 1024 + n0 + 16 + nB)) * 384 + cs8;

    auto stage = [&](int Tn, int slot) {
        int kk = Tn * 32;
        int ck = (kk >= 384) ? kk - 384 : kk;  // 2-part split: B repeats
        async16(pA0 + kk, &As[slot][dst0]);
        async16(pA1 + kk, &As[slot][2048 + dst0]);
        async16(pB0 + ck, &Bs[slot][dst0]);
        async16(pB1 + ck, &Bs[slot][2048 + dst0]);
    };

    // fragment reads: row = base + l15, chunk = quad ^ ((row>>1)&3); bases
    // are multiples of 16 so (row>>1)&3 = (l15>>1)&3 for all frags.
    const int ch = (quad ^ ((l15 >> 1) & 3)) * 8;
    const int arow_ = (wm2 * 64 + l15) * 32 + ch;   // + i*512
    const int bcol_ = (wn2 * 64 + l15) * 32 + ch;   // + t*512

    f32x4 acc[4][4];  // [row-frag i][t]
#pragma unroll
    for (int i = 0; i < 4; i++)
#pragma unroll
        for (int j = 0; j < 4; j++) acc[i][j] = (f32x4){0.f, 0.f, 0.f, 0.f};

    // prologue: stage tiles 0,1; publish slot 0 (tile 1 stays in flight)
    stage(0, 0);
    stage(1, 1);
    asm volatile("s_waitcnt vmcnt(4)\n\ts_barrier" ::: "memory");

    int r = 0, r2v = 2;
#pragma unroll 1
    for (int Tn = 0; Tn < 24; Tn++) {
        short8v af[4], bf[4];
#pragma unroll
        for (int i = 0; i < 4; i++) af[i] = *(const short8v*)&As[r][arow_ + i * 512];
#pragma unroll
        for (int t = 0; t < 4; t++) bf[t] = *(const short8v*)&Bs[r][bcol_ + t * 512];
        // stage tile T+2 into slot r2v (its readers finished before the
        // end-of-tile barrier of Tn-1 -> race-free)
        if (Tn < 22) stage(Tn + 2, r2v);
        __builtin_amdgcn_sched_barrier(0);
        __builtin_amdgcn_s_setprio(1);
#pragma unroll
        for (int i = 0; i < 4; i++)
#pragma unroll
            for (int t = 0; t < 4; t++) acc[i][t] = mfma_f16(af[i], bf[t], acc[i][t]);
        __builtin_amdgcn_s_setprio(0);
        // publish slot of tile Tn+1: tile Tn+2 (4 loads) stays in flight
        if (Tn < 22)       asm volatile("s_waitcnt vmcnt(4)\n\ts_barrier" ::: "memory");
        else if (Tn == 22) asm volatile("s_waitcnt vmcnt(0)\n\ts_barrier" ::: "memory");
        r = (r == 2) ? 0 : r + 1;
        r2v = (r2v == 2) ? 0 : r2v + 1;
    }

    // epilogue: BN + LIF over t (exact numpy order) from accumulators
    const int nn = n0 + wn2 * 16 + l15;
#pragma unroll
    for (int i = 0; i < 4; i++) {
        int co = wm2 * 64 + i * 16 + quad * 4;
        float4 s4 = *(const float4*)&bnS[co];
        float4 m4 = *(const float4*)&bnM[co];
        float4 b4 = *(const float4*)&bnB[co];
        float sc[4] = {s4.x, s4.y, s4.z, s4.w};
        float mn[4] = {m4.x, m4.y, m4.z, m4.w};
        float bt[4] = {b4.x, b4.y, b4.z, b4.w};
        u16 sv[4][4];  // [t][e]
#pragma unroll
        for (int e = 0; e < 4; e++) {
            float vv = 0.0f;
#pragma unroll
            for (int t = 0; t < 4; t++) {
                float a = acc[i][t][e];
                a = __fadd_rn(__fmul_rn(__fsub_rn(a, mn[e]), sc[e]), bt[e]);
                vv = __fadd_rn(vv, __fmul_rn(__fsub_rn(a, vv), 0.5f));
                bool sp = (vv >= 0.5f);
                vv = sp ? 0.0f : vv;
                sv[t][e] = sp ? SPIKE_B : (u16)0;
            }
        }
#pragma unroll
        for (int t = 0; t < 4; t++) {
            ushort4 o4;
            o4.x = sv[t][0]; o4.y = sv[t][1]; o4.z = sv[t][2]; o4.w = sv[t][3];
            *(ushort4*)(dstp + ((size_t)((t * 8 + b) * 1024 + nn)) * 384 + o0 + co) = o4;
        }
    }
}

// ---------------------------------------------------------------------------
// K3: kv partial counts, ATOMIC-FREE. Counts are integers -> exact in fp32.
// Block (nc, tb): 384 thr, tid = rr*48 + c8. Per-rr LDS slab + tree sum,
// then one coalesced 384-float partial row to r2[tb][nc][384].
// ---------------------------------------------------------------------------
__global__ void kvred_kernel(const u16* __restrict__ ks, const u16* __restrict__ vs,
                             float* __restrict__ r2) {
    __shared__ float red[8][384];
    int tb = blockIdx.y, nc = blockIdx.x;
    int tid = threadIdx.x;
    int rr = tid / 48, c8 = tid % 48;

    float cnt[8];
#pragma unroll
    for (int e = 0; e < 8; e++) cnt[e] = 0.0f;

    size_t base = ((size_t)(tb * 1024 + nc * 64 + rr)) * 384 + c8 * 8;
#pragma unroll 2
    for (int it = 0; it < 8; it++) {
        size_t off = base + (size_t)it * 8 * 384;
        uint4 ka = *(const uint4*)(ks + off);
        uint4 va = *(const uint4*)(vs + off);
        uint32_t w0 = ka.x & va.x, w1 = ka.y & va.y, w2 = ka.z & va.z, w3 = ka.w & va.w;
        const uint32_t S = SPIKE_B;
        if ((w0 & 0xFFFFu) == S) cnt[0] += 1.0f;
        if ((w0 >> 16) == S)     cnt[1] += 1.0f;
        if ((w1 & 0xFFFFu) == S) cnt[2] += 1.0f;
        if ((w1 >> 16) == S)     cnt[3] += 1.0f;
        if ((w2 & 0xFFFFu) == S) cnt[4] += 1.0f;
        if ((w2 >> 16) == S)     cnt[5] += 1.0f;
        if ((w3 & 0xFFFFu) == S) cnt[6] += 1.0f;
        if ((w3 >> 16) == S)     cnt[7] += 1.0f;
    }
#pragma unroll
    for (int e = 0; e < 8; e++) red[rr][c8 * 8 + e] = cnt[e];  // unique slots
    __syncthreads();
    float s = 0.0f;
#pragma unroll
    for (int q = 0; q < 8; q++) s += red[q][tid];
    r2[((size_t)(tb * 16 + nc)) * 384 + tid] = s;  // coalesced, no atomics
}

// K3b: r[tb][c] = sum_nc r2[tb][nc][c]. Coalesced over c, 16 independent
// loads/thread, 48 blocks. Integer counts -> order-free exact.
__global__ void ncsum_kernel(const float* __restrict__ r2, float* __restrict__ r) {
    int id = blockIdx.x * 256 + threadIdx.x;
    if (id >= 32 * 384) return;
    int tb = id / 384, c = id % 384;
    const float* p = r2 + ((size_t)(tb * 16)) * 384 + c;
    float s = 0.0f;
#pragma unroll
    for (int nc = 0; nc < 16; nc++) s += p[nc * 384];
    r[id] = s;
}

// K4: talking heads (8x8 fp32) + LIF over t -> kvs[t,b,c] bf16 {0,1} mask
__global__ void talking_kernel(const float* __restrict__ r, const float* __restrict__ th,
                               u16* __restrict__ kvs) {
    int id = blockIdx.x * 256 + threadIdx.x;
    if (id >= 8 * 384) return;
    int b = id / 384, c = id % 384;
    int oh = c / 48, d = c % 48;
    float v = 0.0f;
    for (int t = 0; t < 4; t++) {
        const float* rr = r + (t * 8 + b) * 384 + d;
        float s = 0.0f;
#pragma unroll
        for (int h = 0; h < 8; h++) s = __fmaf_rn(th[oh * 8 + h], rr[h * 48], s);
        v = __fadd_rn(v, __fmul_rn(__fsub_rn(s, v), 0.5f));
        bool sp = (v >= 0.5f);
        v = sp ? 0.0f : v;
        kvs[(t * 8 + b) * 384 + c] = sp ? SPIKE_B : (u16)0;
    }
}

// ---------------------------------------------------------------------------
// K5: proj conv (K=384 bf16) + fused kvs gate + bias + BN + residual.
// 128x128 tiles, ring-of-2, issue-early prefetch (T14), reg-dbuf k-halves,
// ONE barrier/tile, BN tables in LDS. grid (nt=8, mt=3, tb=32), 2 blk/CU.
// ---------------------------------------------------------------------------
__global__ __launch_bounds__(256, 2) void proj_kernel(
    const u16* __restrict__ Aproj, const u16* __restrict__ qs, const u16* __restrict__ kvs,
    const float* __restrict__ xin,
    const float* __restrict__ pb, const float* __restrict__ pg, const float* __restrict__ pbe,
    const float* __restrict__ pm, const float* __restrict__ pv, float* __restrict__ out) {
    __shared__ __align__(16) u16 At[2][8192];
    __shared__ __align__(16) u16 Bt[2][8192];
    __shared__ float eS[128], eM[128], eB[128], eBi[128];

    int tb = blockIdx.z, mt = blockIdx.y, nt = blockIdx.x;
    int m0 = mt * 128, n0 = nt * 128;
    int tid = threadIdx.x, wave = tid >> 6, lane = tid & 63;
    int l15 = lane & 15, quad = lane >> 4;
    int wm = (wave & 1) * 64, wn = (wave >> 1) * 64;

    const u16* Bsrc = qs + ((size_t)(tb * 1024 + n0)) * 384;
    const u16* mbase = kvs + tb * 384;

    if (tid < 128) {
        int o = m0 + tid;
        eS[tid] = pg[o] / sqrtf(pv[o] + 1e-5f);
        eM[tid] = pm[o];
        eB[tid] = pbe[o];
        eBi[tid] = pb[o];
    }

    auto stage = [&](int s) {
        int kk = s * 64;
        int buf = s & 1;
#pragma unroll
        for (int ii = 0; ii < 4; ii++) {
            int l = ii * 256 + tid;
            int row = l >> 3;
            int cs = (l & 7) ^ (row & 7);
            async16(Aproj + (size_t)(m0 + row) * 384 + kk + cs * 8, &At[buf][l * 8]);
            async16(Bsrc + (size_t)row * 384 + kk + cs * 8, &Bt[buf][l * 8]);
        }
    };

    f32x4 acc[4][4];
#pragma unroll
    for (int i = 0; i < 4; i++)
#pragma unroll
        for (int j = 0; j < 4; j++) acc[i][j] = (f32x4){0.f, 0.f, 0.f, 0.f};

    stage(0);
    __syncthreads();  // stage0 landed + tables published

#pragma unroll 1
    for (int kkb = 0; kkb < 6; kkb++) {
        int buf = kkb & 1;
        int kk = kkb * 64;
        // issue next tile FIRST: its vmcnt(0) drain at tile end hides under
        // this tile's reads + 32 MFMAs (buf^1's readers done at end of kkb-1)
        if (kkb < 5) stage(kkb + 1);
        __builtin_amdgcn_sched_barrier(0);

        short8v msk0 = *(const short8v*)(mbase + kk + quad * 8);
        short8v msk1 = *(const short8v*)(mbase + kk + (4 + quad) * 8);
        short8v afA[4], bfA[4], afB[4], bfB[4];
#pragma unroll
        for (int i = 0; i < 4; i++) {
            int row = wm + i * 16 + l15;
            afA[i] = *(const short8v*)&At[buf][row * 64 + ((quad) ^ (row & 7)) * 8];
            afB[i] = *(const short8v*)&At[buf][row * 64 + ((4 + quad) ^ (row & 7)) * 8];
        }
#pragma unroll
        for (int j = 0; j < 4; j++) {
            int nr = wn + j * 16 + l15;
            bfA[j] = *(const short8v*)&Bt[buf][nr * 64 + ((quad) ^ (nr & 7)) * 8] & msk0;
            bfB[j] = *(const short8v*)&Bt[buf][nr * 64 + ((4 + quad) ^ (nr & 7)) * 8] & msk1;
        }
        __builtin_amdgcn_sched_barrier(0);
        __builtin_amdgcn_s_setprio(1);
#pragma unroll
        for (int i = 0; i < 4; i++)
#pragma unroll
            for (int j = 0; j < 4; j++) acc[i][j] = mfma_bf16(afA[i], bfA[j], acc[i][j]);
        __builtin_amdgcn_s_setprio(0);
        __builtin_amdgcn_sched_barrier(0);
        __builtin_amdgcn_s_setprio(1);
#pragma unroll
        for (int i = 0; i < 4; i++)
#pragma unroll
            for (int j = 0; j < 4; j++) acc[i][j] = mfma_bf16(afB[i], bfB[j], acc[i][j]);
        __builtin_amdgcn_s_setprio(0);
        // publish buf^1 for tile kkb+1 (ring-of-2: nothing newer to count)
        if (kkb < 5) asm volatile("s_waitcnt vmcnt(0)\n\ts_barrier" ::: "memory");
    }

    // epilogue: y = conv+bias; (y-mean)*scale+beta; + identity (numpy order)
#pragma unroll
    for (int i = 0; i < 4; i++) {
#pragma unroll
        for (int e = 0; e < 4; e++) {
            int co = wm + i * 16 + quad * 4 + e;
            int o = m0 + co;
            float scale = eS[co], mean = eM[co], beta = eB[co], bias = eBi[co];
#pragma unroll
            for (int j = 0; j < 4; j++) {
                int n = n0 + wn + j * 16 + l15;
                size_t idx = ((size_t)tb * 384 + o) * 1024 + n;
                float y = __fadd_rn(acc[i][j][e], bias);
                y = __fadd_rn(__fmul_rn(__fsub_rn(y, mean), scale), beta);
                out[idx] = __fadd_rn(y, xin[idx]);
            }
        }
    }
}

// ---------------------------------------------------------------------------
extern "C" void kernel_launch(void* const* d_in, const int* in_sizes, int n_in,
                              void* d_out, int out_size, void* d_ws, size_t ws_size,
                              hipStream_t stream) {
    (void)in_sizes; (void)n_in; (void)out_size; (void)ws_size;
    const float* x  = (const float*)d_in[0];
    const float* qw = (const float*)d_in[1];
    const float* kw = (const float*)d_in[2];
    const float* vw = (const float*)d_in[3];
    const float* th = (const float*)d_in[4];
    const float* pw = (const float*)d_in[5];
    const float* pb = (const float*)d_in[6];
    const float* qg = (const float*)d_in[7],  *qbe = (const float*)d_in[8];
    const float* qm = (const float*)d_in[9],  *qv  = (const float*)d_in[10];
    const float* kg = (const float*)d_in[11], *kbe = (const float*)d_in[12];
    const float* km = (const float*)d_in[13], *kv_ = (const float*)d_in[14];
    const float* vg = (const float*)d_in[15], *vbe = (const float*)d_in[16];
    const float* vm = (const float*)d_in[17], *vv_ = (const float*)d_in[18];
    const float* pg = (const float*)d_in[19], *pbe = (const float*)d_in[20];
    const float* pm = (const float*)d_in[21], *pv  = (const float*)d_in[22];
    float* out = (float*)d_out;

    char* w = (char*)d_ws;
    const size_t SPIKES = (size_t)32 * 1024 * 384 * 2;  // 25,165,824 B each
    u16* xs    = (u16*)(w);
    u16* qs    = (u16*)(w + SPIKES);
    u16* ks    = (u16*)(w + 2 * SPIKES);
    u16* vs    = (u16*)(w + 3 * SPIKES);
    u16* Ah    = (u16*)(w + 4 * SPIKES);                         // 1,769,472 B
    u16* Aproj = (u16*)(w + 4 * SPIKES + 1769472);               //   294,912 B
    float* r2  = (float*)(w + 4 * SPIKES + 1769472 + 294912);    //   786,432 B
    float* r   = (float*)(w + 4 * SPIKES + 1769472 + 294912 + 786432);  // 49,152 B
    u16* kvs   = (u16*)(w + 4 * SPIKES + 1769472 + 294912 + 786432 + 49152);  // 24,576 B

    prep_kernel<<<1728, 256, 0, stream>>>(qw, kw, vw, pw, Ah, Aproj);
    lifx_kernel<<<dim3(16, 6, 8), 256, 0, stream>>>(x, xs);
    qkv_kernel<<<dim3(32, 9, 8), 256, 0, stream>>>(Ah, xs, qs, ks, vs,
                                                   qg, qbe, qm, qv,
                                                   kg, kbe, km, kv_,
                                                   vg, vbe, vm, vv_);
    kvred_kernel<<<dim3(16, 32), 384, 0, stream>>>(ks, vs, r2);
    ncsum_kernel<<<48, 256, 0, stream>>>(r2, r);
    talking_kernel<<<12, 256, 0, stream>>>(r, th, kvs);
    proj_kernel<<<dim3(8, 3, 32), 256, 0, stream>>>(Aproj, qs, kvs, x, pb, pg, pbe, pm, pv, out);
}